// Round 5
// baseline (193.927 us; speedup 1.0000x reference)
//
#include <hip/hip_runtime.h>

// DenseLayerWithComplexNeurons: out = per-cell-type-MLP( x @ W^T + b )
// M = B*S = 8192, K = DIN = 1024, N = A*DOUT = 4096, DOUT = 1024
// T = 4 cell types, G = 256 neurons/type, A = 4, H = 8.
//
// R1: 128x128/BK64 + fused LDS epilogue. 154.5us, 2.5e7 conflicts.
// R2: XOR-swizzled staging -> 0 conflicts, 118.9us.
// R3: 256x128, 128x64 wave tiles, 32x32x16 MFMA. 101.2us (2 blocks/CU).
//     6.29e6 conflicts = K-loop frag reads (32 rows x 128B stride = 4-way).
// R4: 256x256, 128KB dbuf, 1 block/CU. 115.6us REGRESSION: pipelining
//     gained less than the co-residency it destroyed. TLP > dbuf.
// R5: R3 shape + BK=32 double-buffer (2x24KB = 48KB, same as R3 -> still
//     2 blocks/CU). 1 barrier/iter; tile k+1 loads fly across a full
//     compute phase. 64B rows -> frag reads back to 2-way (free).

typedef __bf16 bf16x8 __attribute__((ext_vector_type(8)));
typedef float f32x4 __attribute__((ext_vector_type(4)));
typedef float f32x16 __attribute__((ext_vector_type(16)));

#define BM 256
#define BN 128
#define BK 32
#define KDIM 1024
#define NITER (KDIM / BK)           // 32
#define ABUF (BM * BK)              // 8192 elems (16 KB)
#define BUF_ELEMS ((BM + BN) * BK)  // 12288 elems
#define BUF_BYTES (BUF_ELEMS * 2)   // 24576 B
#define ZS 132                      // z row stride (floats)
#define XN8 (8192 * 1024 / 8)
#define WN8 (4096 * 1024 / 8)

__global__ __launch_bounds__(256) void cvt_bf16_kernel(
    const float* __restrict__ x, const float* __restrict__ w,
    __bf16* __restrict__ xb, __bf16* __restrict__ wb) {
    int i = blockIdx.x * 256 + threadIdx.x;
    const float* src;
    __bf16* dst;
    int j;
    if (i < XN8) { src = x; dst = xb; j = i; }
    else         { src = w; dst = wb; j = i - XN8; }
    const f32x4* p = (const f32x4*)src + 2 * (size_t)j;
    f32x4 a = p[0], b = p[1];
    bf16x8 o;
    o[0] = (__bf16)a[0]; o[1] = (__bf16)a[1]; o[2] = (__bf16)a[2]; o[3] = (__bf16)a[3];
    o[4] = (__bf16)b[0]; o[5] = (__bf16)b[1]; o[6] = (__bf16)b[2]; o[7] = (__bf16)b[3];
    ((bf16x8*)dst)[j] = o;
}

union __align__(16) SmemU {
    __bf16 stg[2 * BUF_ELEMS];   // 48 KB: two {A(256x32)|B(128x32)} buffers
                                 // rows are 64B = 4 chunks of 16B; chunk c at c^(row&3)
    float  z[64 * ZS];           // one 64-row slab of the z tile (33.8 KB, aliases)
};

__global__ __launch_bounds__(256, 2) void fused_gemm_mlp_kernel(
    const __bf16* __restrict__ Ag,   // [8192][1024] bf16 (x)
    const __bf16* __restrict__ Bg,   // [4096][1024] bf16 (weight, already B^T layout)
    const float* __restrict__ bias,  // [4096]
    const float* __restrict__ cw1,   // [4][4][8]
    const float* __restrict__ cb1,   // [4][8]
    const float* __restrict__ cw2,   // [4][8]
    const float* __restrict__ cb2,   // [4]
    float* __restrict__ out)         // [8192][1024]
{
    __shared__ SmemU u;

    const int tid  = threadIdx.x;
    const int wave = tid >> 6;
    const int lane = tid & 63;
    const int wm = wave >> 1;        // row half (0..1): 128 rows each
    const int wn = wave & 1;         // col half (0..1): 64 cols each
    const int bn0 = blockIdx.x * BN; // n offset in [0,4096)
    const int bm0 = blockIdx.y * BM; // m offset in [0,8192)

    f32x16 acc[4][2] = {};           // 4 m-tiles x 2 n-tiles of 32x32

    // staging lane mapping: 16-row chunks of 1KB; lane -> row chunk*16+(lane>>2),
    // fetches GLOBAL 16B-chunk ((lane&3) ^ (row&3)) of that row's 64B segment.
    const int srow4 = lane >> 2;
    const int g8    = (((lane & 3) ^ (srow4 & 3)) * 8);  // element offset

    // fragment LDS addressing (row R, global k-chunk kc lives at slot kc^(R&3))
    const int lr5 = lane & 31;
    const int lk2 = lane >> 5;   // 0..1
    const int lx2 = lane & 3;
    const int arow = (wm * 128 + lr5) * (BK * 2);              // bytes
    const int brow = ABUF * 2 + (wn * 64 + lr5) * (BK * 2);    // bytes
    int cxo[2];
#pragma unroll
    for (int kh = 0; kh < 2; ++kh)
        cxo[kh] = ((kh * 2 + lk2) ^ lx2) * 16;
    const char* sb = (const char*)u.stg;

    auto stage = [&](int it, int buf) {
        __bf16* dstA = u.stg + buf * BUF_ELEMS;
        __bf16* dstB = dstA + ABUF;
        const int kof = it * BK;
#pragma unroll
        for (int c = 0; c < 4; ++c) {          // A: 16 chunks of 16 rows, 4/wave
            const int chunk = wave * 4 + c;
            const __bf16* ga = Ag + (size_t)(bm0 + chunk * 16 + srow4) * KDIM + kof + g8;
            __builtin_amdgcn_global_load_lds(
                (__attribute__((address_space(1))) void*)ga,
                (__attribute__((address_space(3))) void*)&dstA[chunk * 512],
                16, 0, 0);
        }
#pragma unroll
        for (int c = 0; c < 2; ++c) {          // B: 8 chunks of 16 rows, 2/wave
            const int chunk = wave * 2 + c;
            const __bf16* gb = Bg + (size_t)(bn0 + chunk * 16 + srow4) * KDIM + kof + g8;
            __builtin_amdgcn_global_load_lds(
                (__attribute__((address_space(1))) void*)gb,
                (__attribute__((address_space(3))) void*)&dstB[chunk * 512],
                16, 0, 0);
        }
    };

    stage(0, 0);
    for (int it = 0; it < NITER; ++it) {
        // barrier's vmcnt(0) drains loads issued LAST iteration (a full
        // compute phase ago); buffer (it+1)&1 is no longer being read.
        __syncthreads();
        if (it + 1 < NITER) stage(it + 1, (it + 1) & 1);
        const char* base = sb + (it & 1) * BUF_BYTES;
#pragma unroll
        for (int kh = 0; kh < 2; ++kh) {
            bf16x8 af[4], bfr[2];
#pragma unroll
            for (int mi = 0; mi < 4; ++mi)
                af[mi] = *(const bf16x8*)(base + arow + mi * 2048 + cxo[kh]);
#pragma unroll
            for (int ni = 0; ni < 2; ++ni)
                bfr[ni] = *(const bf16x8*)(base + brow + ni * 2048 + cxo[kh]);
#pragma unroll
            for (int mi = 0; mi < 4; ++mi)
#pragma unroll
                for (int ni = 0; ni < 2; ++ni)
                    acc[mi][ni] = __builtin_amdgcn_mfma_f32_32x32x16_bf16(
                        af[mi], bfr[ni], acc[mi][ni], 0, 0, 0);
        }
    }
    __syncthreads();  // all LDS reads done before z overwrites stg

    // ---- epilogue: per-neuron MLP over A=4 adjacent z columns ----
    const int t = bn0 >> 10;  // cell type, block-uniform
    const float L2E2 = 2.885390081777927f;  // 2*log2(e)
    float w1s[32], b1s[8], w2m[8];
#pragma unroll
    for (int i = 0; i < 32; ++i) w1s[i] = cw1[t * 32 + i] * L2E2;
    float oinit = cb2[t];
#pragma unroll
    for (int i = 0; i < 8; ++i) {
        b1s[i] = cb1[t * 8 + i] * L2E2;
        w2m[i] = -2.0f * cw2[t * 8 + i];
        oinit += cw2[t * 8 + i];
    }

    float bcol[2];
#pragma unroll
    for (int ni = 0; ni < 2; ++ni)
        bcol[ni] = bias[bn0 + wn * 64 + ni * 32 + lr5];

#pragma unroll
    for (int h = 0; h < 4; ++h) {  // 64-row slabs of the 256-row tile
        if (wm == (h >> 1)) {
#pragma unroll
            for (int dmi = 0; dmi < 2; ++dmi) {
                const int mi = (h & 1) * 2 + dmi;
#pragma unroll
                for (int ni = 0; ni < 2; ++ni) {
                    const int n = wn * 64 + ni * 32 + lr5;
#pragma unroll
                    for (int g = 0; g < 4; ++g) {
                        // C/D 32x32: col=lane&31, row=(reg&3)+8*(reg>>2)+4*(lane>>5)
                        const int rb = dmi * 32 + g * 8 + lk2 * 4;
                        u.z[(rb + 0) * ZS + n] = acc[mi][ni][g * 4 + 0] + bcol[ni];
                        u.z[(rb + 1) * ZS + n] = acc[mi][ni][g * 4 + 1] + bcol[ni];
                        u.z[(rb + 2) * ZS + n] = acc[mi][ni][g * 4 + 2] + bcol[ni];
                        u.z[(rb + 3) * ZS + n] = acc[mi][ni][g * 4 + 3] + bcol[ni];
                    }
                }
            }
        }
        __syncthreads();

        // 64 rows x 32 neurons = 2048 outputs; 8 per thread
#pragma unroll
        for (int it2 = 0; it2 < 8; ++it2) {
            const int i = tid + it2 * 256;
            const int q = i & 31;       // neuron within block
            const int r = i >> 5;       // row within slab
            f32x4 z = *(const f32x4*)&u.z[r * ZS + 4 * q];
            float o = oinit;
#pragma unroll
            for (int hh = 0; hh < 8; ++hh) {
                float pre = z[0] * w1s[0 * 8 + hh] + z[1] * w1s[1 * 8 + hh]
                          + z[2] * w1s[2 * 8 + hh] + z[3] * w1s[3 * 8 + hh] + b1s[hh];
                float e = __builtin_amdgcn_exp2f(pre);               // e^(2*pre)
                o += w2m[hh] * __builtin_amdgcn_rcpf(e + 1.0f);      // o += -2*w2*sigmoid-ish
            }
            out[(size_t)(bm0 + h * 64 + r) * 1024 + (bn0 >> 2) + q] = o;
        }
        __syncthreads();
    }
}

extern "C" void kernel_launch(void* const* d_in, const int* in_sizes, int n_in,
                              void* d_out, int out_size, void* d_ws, size_t ws_size,
                              hipStream_t stream) {
    const float* x    = (const float*)d_in[0];
    const float* w    = (const float*)d_in[1];
    const float* bias = (const float*)d_in[2];
    const float* cw1  = (const float*)d_in[3];
    const float* cb1  = (const float*)d_in[4];
    const float* cw2  = (const float*)d_in[5];
    const float* cb2  = (const float*)d_in[6];
    float* out = (float*)d_out;

    __bf16* xb = (__bf16*)d_ws;                       // 8192*1024 bf16 = 16 MB
    __bf16* wb = xb + (size_t)8192 * 1024;            // 4096*1024 bf16 = 8 MB

    cvt_bf16_kernel<<<(XN8 + WN8) / 256, 256, 0, stream>>>(x, w, xb, wb);

    dim3 grid(4096 / BN, 8192 / BM);  // (32, 32) = 1024 blocks
    fused_gemm_mlp_kernel<<<grid, 256, 0, stream>>>(xb, wb, bias, cw1, cb1, cw2, cb2, out);
}

// Round 6
// 189.678 us; speedup vs baseline: 1.0224x; 1.0224x over previous
//
#include <hip/hip_runtime.h>

// DenseLayerWithComplexNeurons: out = per-cell-type-MLP( x @ W^T + b )
// M = B*S = 8192, K = DIN = 1024, N = A*DOUT = 4096, DOUT = 1024
// T = 4 cell types, G = 256 neurons/type, A = 4, H = 8.
//
// R1: 128x128/BK64 + fused LDS epilogue. 154.5us, 2.5e7 conflicts.
// R2: XOR-swizzled staging -> 0 conflicts, 118.9us.
// R3: 256x128, 128x64 wave tiles, 32x32x16 MFMA. 101.2us (2 blocks/CU).
// R4: 256x256, 128KB dbuf, 1 block/CU. 115.6us REGRESSION. TLP > dbuf.
// R5: R3 + BK=32 dbuf (48KB). 103.4us, conflicts 3x: 64B rows + r&3 XOR
//     -> rows r,r+4 alias -> frag reads hit only 16 banks (2x LDS time).
// R6: swizzle on (r>>1)&3: store chunk c of row r at slot c^((r>>1)&3).
//     Frag-read bank-quad = 16*(r&1)+4*(kc^((r>>1)&3)) = bijection over all
//     8 quads for r mod 8 -> uniform banks again. Rest identical to R5.

typedef __bf16 bf16x8 __attribute__((ext_vector_type(8)));
typedef float f32x4 __attribute__((ext_vector_type(4)));
typedef float f32x16 __attribute__((ext_vector_type(16)));

#define BM 256
#define BN 128
#define BK 32
#define KDIM 1024
#define NITER (KDIM / BK)           // 32
#define ABUF (BM * BK)              // 8192 elems (16 KB)
#define BUF_ELEMS ((BM + BN) * BK)  // 12288 elems
#define BUF_BYTES (BUF_ELEMS * 2)   // 24576 B
#define ZS 132                      // z row stride (floats)
#define XN8 (8192 * 1024 / 8)
#define WN8 (4096 * 1024 / 8)

__global__ __launch_bounds__(256) void cvt_bf16_kernel(
    const float* __restrict__ x, const float* __restrict__ w,
    __bf16* __restrict__ xb, __bf16* __restrict__ wb) {
    int i = blockIdx.x * 256 + threadIdx.x;
    const float* src;
    __bf16* dst;
    int j;
    if (i < XN8) { src = x; dst = xb; j = i; }
    else         { src = w; dst = wb; j = i - XN8; }
    const f32x4* p = (const f32x4*)src + 2 * (size_t)j;
    f32x4 a = p[0], b = p[1];
    bf16x8 o;
    o[0] = (__bf16)a[0]; o[1] = (__bf16)a[1]; o[2] = (__bf16)a[2]; o[3] = (__bf16)a[3];
    o[4] = (__bf16)b[0]; o[5] = (__bf16)b[1]; o[6] = (__bf16)b[2]; o[7] = (__bf16)b[3];
    ((bf16x8*)dst)[j] = o;
}

union __align__(16) SmemU {
    __bf16 stg[2 * BUF_ELEMS];   // 48 KB: two {A(256x32)|B(128x32)} buffers
                                 // rows = 64B = 4 chunks of 16B; chunk c at slot c^((r>>1)&3)
    float  z[64 * ZS];           // one 64-row slab of the z tile (33.8 KB, aliases)
};

__global__ __launch_bounds__(256, 2) void fused_gemm_mlp_kernel(
    const __bf16* __restrict__ Ag,   // [8192][1024] bf16 (x)
    const __bf16* __restrict__ Bg,   // [4096][1024] bf16 (weight, already B^T layout)
    const float* __restrict__ bias,  // [4096]
    const float* __restrict__ cw1,   // [4][4][8]
    const float* __restrict__ cb1,   // [4][8]
    const float* __restrict__ cw2,   // [4][8]
    const float* __restrict__ cb2,   // [4]
    float* __restrict__ out)         // [8192][1024]
{
    __shared__ SmemU u;

    const int tid  = threadIdx.x;
    const int wave = tid >> 6;
    const int lane = tid & 63;
    const int wm = wave >> 1;        // row half (0..1): 128 rows each
    const int wn = wave & 1;         // col half (0..1): 64 cols each
    const int bn0 = blockIdx.x * BN; // n offset in [0,4096)
    const int bm0 = blockIdx.y * BM; // m offset in [0,8192)

    f32x16 acc[4][2] = {};           // 4 m-tiles x 2 n-tiles of 32x32

    // staging lane mapping: 16-row chunks of 1KB; lane -> row chunk*16+(lane>>2).
    // LDS slot (lane&3) must receive global chunk (lane&3)^((row>>1)&3);
    // (row>>1)&3 == (lane>>3)&3 within the 16-row chunk (chunk*16 is 0 mod 8 rows).
    const int srow4 = lane >> 2;
    const int g8    = (((lane & 3) ^ ((lane >> 3) & 3)) * 8);  // element offset

    // fragment LDS addressing: global k-chunk kc of row r lives at slot kc^((r>>1)&3);
    // r within tile = lr5 (+ multiples of 32 rows -> swizzle index unchanged).
    const int lr5 = lane & 31;
    const int lk2 = lane >> 5;   // 0..1
    const int sw2 = (lr5 >> 1) & 3;
    const int arow = (wm * 128 + lr5) * (BK * 2);              // bytes
    const int brow = ABUF * 2 + (wn * 64 + lr5) * (BK * 2);    // bytes
    int cxo[2];
#pragma unroll
    for (int kh = 0; kh < 2; ++kh)
        cxo[kh] = ((kh * 2 + lk2) ^ sw2) * 16;
    const char* sb = (const char*)u.stg;

    auto stage = [&](int it, int buf) {
        __bf16* dstA = u.stg + buf * BUF_ELEMS;
        __bf16* dstB = dstA + ABUF;
        const int kof = it * BK;
#pragma unroll
        for (int c = 0; c < 4; ++c) {          // A: 16 chunks of 16 rows, 4/wave
            const int chunk = wave * 4 + c;
            const __bf16* ga = Ag + (size_t)(bm0 + chunk * 16 + srow4) * KDIM + kof + g8;
            __builtin_amdgcn_global_load_lds(
                (__attribute__((address_space(1))) void*)ga,
                (__attribute__((address_space(3))) void*)&dstA[chunk * 512],
                16, 0, 0);
        }
#pragma unroll
        for (int c = 0; c < 2; ++c) {          // B: 8 chunks of 16 rows, 2/wave
            const int chunk = wave * 2 + c;
            const __bf16* gb = Bg + (size_t)(bn0 + chunk * 16 + srow4) * KDIM + kof + g8;
            __builtin_amdgcn_global_load_lds(
                (__attribute__((address_space(1))) void*)gb,
                (__attribute__((address_space(3))) void*)&dstB[chunk * 512],
                16, 0, 0);
        }
    };

    stage(0, 0);
    for (int it = 0; it < NITER; ++it) {
        // barrier's vmcnt(0) drains loads issued LAST iteration (a full
        // compute phase ago); buffer (it+1)&1 is no longer being read.
        __syncthreads();
        if (it + 1 < NITER) stage(it + 1, (it + 1) & 1);
        const char* base = sb + (it & 1) * BUF_BYTES;
#pragma unroll
        for (int kh = 0; kh < 2; ++kh) {
            bf16x8 af[4], bfr[2];
#pragma unroll
            for (int mi = 0; mi < 4; ++mi)
                af[mi] = *(const bf16x8*)(base + arow + mi * 2048 + cxo[kh]);
#pragma unroll
            for (int ni = 0; ni < 2; ++ni)
                bfr[ni] = *(const bf16x8*)(base + brow + ni * 2048 + cxo[kh]);
#pragma unroll
            for (int mi = 0; mi < 4; ++mi)
#pragma unroll
                for (int ni = 0; ni < 2; ++ni)
                    acc[mi][ni] = __builtin_amdgcn_mfma_f32_32x32x16_bf16(
                        af[mi], bfr[ni], acc[mi][ni], 0, 0, 0);
        }
    }
    __syncthreads();  // all LDS reads done before z overwrites stg

    // ---- epilogue: per-neuron MLP over A=4 adjacent z columns ----
    const int t = bn0 >> 10;  // cell type, block-uniform
    const float L2E2 = 2.885390081777927f;  // 2*log2(e)
    float w1s[32], b1s[8], w2m[8];
#pragma unroll
    for (int i = 0; i < 32; ++i) w1s[i] = cw1[t * 32 + i] * L2E2;
    float oinit = cb2[t];
#pragma unroll
    for (int i = 0; i < 8; ++i) {
        b1s[i] = cb1[t * 8 + i] * L2E2;
        w2m[i] = -2.0f * cw2[t * 8 + i];
        oinit += cw2[t * 8 + i];
    }

    float bcol[2];
#pragma unroll
    for (int ni = 0; ni < 2; ++ni)
        bcol[ni] = bias[bn0 + wn * 64 + ni * 32 + lr5];

#pragma unroll
    for (int h = 0; h < 4; ++h) {  // 64-row slabs of the 256-row tile
        if (wm == (h >> 1)) {
#pragma unroll
            for (int dmi = 0; dmi < 2; ++dmi) {
                const int mi = (h & 1) * 2 + dmi;
#pragma unroll
                for (int ni = 0; ni < 2; ++ni) {
                    const int n = wn * 64 + ni * 32 + lr5;
#pragma unroll
                    for (int g = 0; g < 4; ++g) {
                        // C/D 32x32: col=lane&31, row=(reg&3)+8*(reg>>2)+4*(lane>>5)
                        const int rb = dmi * 32 + g * 8 + lk2 * 4;
                        u.z[(rb + 0) * ZS + n] = acc[mi][ni][g * 4 + 0] + bcol[ni];
                        u.z[(rb + 1) * ZS + n] = acc[mi][ni][g * 4 + 1] + bcol[ni];
                        u.z[(rb + 2) * ZS + n] = acc[mi][ni][g * 4 + 2] + bcol[ni];
                        u.z[(rb + 3) * ZS + n] = acc[mi][ni][g * 4 + 3] + bcol[ni];
                    }
                }
            }
        }
        __syncthreads();

        // 64 rows x 32 neurons = 2048 outputs; 8 per thread
#pragma unroll
        for (int it2 = 0; it2 < 8; ++it2) {
            const int i = tid + it2 * 256;
            const int q = i & 31;       // neuron within block
            const int r = i >> 5;       // row within slab
            f32x4 z = *(const f32x4*)&u.z[r * ZS + 4 * q];
            float o = oinit;
#pragma unroll
            for (int hh = 0; hh < 8; ++hh) {
                float pre = z[0] * w1s[0 * 8 + hh] + z[1] * w1s[1 * 8 + hh]
                          + z[2] * w1s[2 * 8 + hh] + z[3] * w1s[3 * 8 + hh] + b1s[hh];
                float e = __builtin_amdgcn_exp2f(pre);               // e^(2*pre)
                o += w2m[hh] * __builtin_amdgcn_rcpf(e + 1.0f);      // o += -2*w2/(e+1)
            }
            out[(size_t)(bm0 + h * 64 + r) * 1024 + (bn0 >> 2) + q] = o;
        }
        __syncthreads();
    }
}

extern "C" void kernel_launch(void* const* d_in, const int* in_sizes, int n_in,
                              void* d_out, int out_size, void* d_ws, size_t ws_size,
                              hipStream_t stream) {
    const float* x    = (const float*)d_in[0];
    const float* w    = (const float*)d_in[1];
    const float* bias = (const float*)d_in[2];
    const float* cw1  = (const float*)d_in[3];
    const float* cb1  = (const float*)d_in[4];
    const float* cw2  = (const float*)d_in[5];
    const float* cb2  = (const float*)d_in[6];
    float* out = (float*)d_out;

    __bf16* xb = (__bf16*)d_ws;                       // 8192*1024 bf16 = 16 MB
    __bf16* wb = xb + (size_t)8192 * 1024;            // 4096*1024 bf16 = 8 MB

    cvt_bf16_kernel<<<(XN8 + WN8) / 256, 256, 0, stream>>>(x, w, xb, wb);

    dim3 grid(4096 / BN, 8192 / BM);  // (32, 32) = 1024 blocks
    fused_gemm_mlp_kernel<<<grid, 256, 0, stream>>>(xb, wb, bias, cw1, cb1, cw2, cb2, out);
}